// Round 1
// baseline (555.499 us; speedup 1.0000x reference)
//
#include <hip/hip_runtime.h>
#include <hip/hip_bf16.h>

// GNN processor: NL=256, NP=8192, NV=16, B=2.
// Strategy: factor first edge layer into S/P/E GEMMs (gather trick), fuse the
// 3 remaining edge layers + NV-aggregation in one LDS-resident MFMA kernel,
// fuse the node MLP + residual in another. All matmuls bf16 MFMA 16x16x32.

typedef __bf16 bf16;
typedef __bf16 bf16x8 __attribute__((ext_vector_type(8)));
typedef float f32x4 __attribute__((ext_vector_type(4)));

#define MFMA16(a, b, c) __builtin_amdgcn_mfma_f32_16x16x32_bf16((a), (b), (c), 0, 0, 0)

constexpr int kNP = 8192;
constexpr int kNV = 16;

// ---------------- weight packing ----------------
// fp32 W[K][N] (as used in x @ W) -> bf16 fragment-ready layout:
// dst[((nt*kd + ks)*64 + lane)*8 + j] = W[ks*32 + (lane>>4)*8 + j][nt*16 + (lane&15)]
// so a wave's B-fragment load is one coalesced 1KB dwordx4 burst (L2-hot).
__global__ void pack_w(const float* __restrict__ src, bf16* __restrict__ dst,
                       int kd, int N) {
  int t = blockIdx.x * 256 + threadIdx.x;
  int j = t & 7;
  int l = (t >> 3) & 63;
  int r2 = t >> 9;
  int ks = r2 % kd;
  int nt = r2 / kd;
  int k = ks * 32 + ((l >> 4) << 3) + j;
  int n = (nt << 4) + (l & 15);
  dst[t] = (bf16)src[k * N + n];
}

// ---------------- MFMA layer primitives ----------------
// Block = 256 threads = 4 waves; wave w owns output cols [64w, 64w+64).
// X is an LDS tile [MT*16 rows][xs stride elems] bf16 (stride K+24 -> row
// starts shift 12 banks -> worst 2-way conflict on ds_read_b128 == free).
// A-frag: a[j] = X[mt*16 + (lane&15)][ks*32 + (lane>>4)*8 + j]
// B-frag: lane-ordered packed global load.
// C/D:    col = lane&15, row = (lane>>4)*4 + i   (verified m89 layout)
template <int KD, int MT>
__device__ __forceinline__ void layer_acc(const bf16* X, int xs,
                                          const bf16* __restrict__ Wp,
                                          const float* __restrict__ bias,
                                          f32x4 (&acc)[MT][4]) {
  const int lane = threadIdx.x & 63;
  const int w = threadIdx.x >> 6;
  const int q = lane >> 4;
  const int c = lane & 15;
#pragma unroll
  for (int nt = 0; nt < 4; nt++) {
    float bv = bias ? bias[w * 64 + nt * 16 + c] : 0.0f;
#pragma unroll
    for (int mt = 0; mt < MT; mt++) {
      acc[mt][nt][0] = bv;
      acc[mt][nt][1] = bv;
      acc[mt][nt][2] = bv;
      acc[mt][nt][3] = bv;
    }
  }
#pragma unroll
  for (int ks = 0; ks < KD; ks++) {
    bf16x8 a[MT];
#pragma unroll
    for (int mt = 0; mt < MT; mt++)
      a[mt] = *(const bf16x8*)(X + (mt * 16 + c) * xs + ks * 32 + q * 8);
    bf16x8 bb[4];
#pragma unroll
    for (int nt = 0; nt < 4; nt++)
      bb[nt] = *(const bf16x8*)(Wp + ((((w * 4 + nt) * KD + ks) * 64 + lane) << 3));
#pragma unroll
    for (int mt = 0; mt < MT; mt++)
#pragma unroll
      for (int nt = 0; nt < 4; nt++)
        acc[mt][nt] = MFMA16(a[mt], bb[nt], acc[mt][nt]);
  }
}

template <int KD, int MT, bool RELU>
__device__ __forceinline__ void layer_inplace(bf16* X, int xs_r, int xs_w,
                                              const bf16* __restrict__ Wp,
                                              const float* __restrict__ bias) {
  f32x4 acc[MT][4];
  layer_acc<KD, MT>(X, xs_r, Wp, bias, acc);
  const int lane = threadIdx.x & 63;
  const int w = threadIdx.x >> 6;
  const int q = lane >> 4;
  const int c = lane & 15;
  __syncthreads();  // all waves done reading X before overwrite
#pragma unroll
  for (int mt = 0; mt < MT; mt++)
#pragma unroll
    for (int nt = 0; nt < 4; nt++)
#pragma unroll
      for (int i = 0; i < 4; i++) {
        float v = acc[mt][nt][i];
        if (RELU) v = fmaxf(v, 0.0f);
        X[(mt * 16 + q * 4 + i) * xs_w + (w * 64 + nt * 16 + c)] = (bf16)v;
      }
  __syncthreads();
}

// ---------------- S / P / E producer GEMM ----------------
// out[m][:] = A_fp32[m][:] @ W (+bias), stored bf16. M = grid*64 rows.
__global__ __launch_bounds__(256) void gemm_fp32in(
    const float* __restrict__ A, const bf16* __restrict__ Wp,
    const float* __restrict__ bias, bf16* __restrict__ out) {
  __shared__ bf16 X[64 * 280];
  const int t = threadIdx.x;
  const int r = t >> 2;   // 64 rows, 4 threads/row
  const int q4 = t & 3;   // 64-col quarter
  const int m = blockIdx.x * 64 + r;
  const float* Arow = A + m * 256 + q4 * 64;
  bf16* Xrow = X + r * 280 + q4 * 64;
#pragma unroll
  for (int c8 = 0; c8 < 8; c8++) {
    float4 f0 = *(const float4*)(Arow + c8 * 8);
    float4 f1 = *(const float4*)(Arow + c8 * 8 + 4);
    bf16x8 v;
    v[0] = (bf16)f0.x; v[1] = (bf16)f0.y; v[2] = (bf16)f0.z; v[3] = (bf16)f0.w;
    v[4] = (bf16)f1.x; v[5] = (bf16)f1.y; v[6] = (bf16)f1.z; v[7] = (bf16)f1.w;
    *(bf16x8*)(Xrow + c8 * 8) = v;
  }
  __syncthreads();
  layer_inplace<8, 4, false>(X, 280, 280, Wp, bias);
  bf16* orow = out + m * 256 + q4 * 64;
#pragma unroll
  for (int c8 = 0; c8 < 8; c8++)
    *(uint4*)(orow + c8 * 8) = *(const uint4*)(Xrow + c8 * 8);
}

// ---------------- fused edge MLP (layers 2..4) + aggregation ----------------
// Row e = ((b*NP + p)*NV + v). Block = 64 rows = 4 complete (b,p) groups.
__global__ __launch_bounds__(256) void edge_mlp(
    const bf16* __restrict__ S, const bf16* __restrict__ P,
    const bf16* __restrict__ E, const int* __restrict__ idx,
    const bf16* __restrict__ Wh0, const bf16* __restrict__ Wh1,
    const bf16* __restrict__ Wl, const float* __restrict__ e_hb,
    const float* __restrict__ e_lb, bf16* __restrict__ agg,
    float* __restrict__ out_edges) {
  __shared__ bf16 X[64 * 280];
  const int t = threadIdx.x;
  const int e0 = blockIdx.x * 64;
  const int b = e0 >> 17;                 // 131072 edges per batch
  const int pbase = (e0 >> 4) & (kNP - 1);
  {
    const int r = t >> 2;
    const int q4 = t & 3;
    const int p = pbase + (r >> 4);
    const int v = r & 15;
    const int nb = idx[p * kNV + v];
    const bf16* Srow = S + ((b << 13) + p) * 256 + q4 * 64;
    const bf16* Prow = P + ((b << 13) + nb) * 256 + q4 * 64;
    const bf16* Erow = E + (p * kNV + v) * 256 + q4 * 64;
    bf16* Xrow = X + r * 280 + q4 * 64;
#pragma unroll
    for (int c8 = 0; c8 < 8; c8++) {
      bf16x8 sv = *(const bf16x8*)(Srow + c8 * 8);
      bf16x8 pv = *(const bf16x8*)(Prow + c8 * 8);
      bf16x8 ev = *(const bf16x8*)(Erow + c8 * 8);
      bf16x8 o;
#pragma unroll
      for (int j = 0; j < 8; j++) {
        float f = (float)sv[j] + (float)pv[j] + (float)ev[j];
        o[j] = (bf16)fmaxf(f, 0.0f);  // relu(layer-1)
      }
      *(bf16x8*)(Xrow + c8 * 8) = o;
    }
  }
  __syncthreads();
  layer_inplace<8, 4, true>(X, 280, 280, Wh0, e_hb);
  layer_inplace<8, 4, true>(X, 280, 280, Wh1, e_hb + 256);
  f32x4 acc[4][4];
  layer_acc<8, 4>(X, 280, Wl, e_lb, acc);
  const int lane = t & 63;
  const int w = t >> 6;
  const int q = lane >> 4;
  const int c = lane & 15;
  // NV-aggregation: each 16-row M-tile is one (b,p) group; rows are v.
#pragma unroll
  for (int mt = 0; mt < 4; mt++) {
#pragma unroll
    for (int nt = 0; nt < 4; nt++) {
      float s = acc[mt][nt][0] + acc[mt][nt][1] + acc[mt][nt][2] + acc[mt][nt][3];
      s += __shfl_xor(s, 16, 64);
      s += __shfl_xor(s, 32, 64);
      if (lane < 16)
        agg[((b << 13) + pbase + mt) * 256 + w * 64 + nt * 16 + lane] = (bf16)s;
    }
  }
  if (b == 0) {  // only batch-0 edges are outputs
#pragma unroll
    for (int mt = 0; mt < 4; mt++)
#pragma unroll
      for (int nt = 0; nt < 4; nt++)
#pragma unroll
        for (int i = 0; i < 4; i++) {
          int e = e0 + mt * 16 + q * 4 + i;
          out_edges[e * 256 + (w * 64 + nt * 16 + c)] = acc[mt][nt][i];
        }
  }
}

// ---------------- fused node MLP + residual ----------------
// 32-row tiles (K=512 first layer would need 68KB LDS at 64 rows).
__global__ __launch_bounds__(256) void node_mlp(
    const float* __restrict__ nodes, const bf16* __restrict__ agg,
    const bf16* __restrict__ Wf, const bf16* __restrict__ Wh0,
    const bf16* __restrict__ Wh1, const bf16* __restrict__ Wl,
    const float* __restrict__ n_fb, const float* __restrict__ n_hb,
    const float* __restrict__ n_lb, float* __restrict__ out_nodes) {
  __shared__ bf16 X[32 * 536];
  const int t = threadIdx.x;
  const int r = t >> 3;   // 32 rows, 8 threads/row
  const int q8 = t & 7;   // 32-col slice
  const int m = blockIdx.x * 32 + r;
  bf16* Xrow = X + r * 536;
  const float* Arow = nodes + m * 256 + q8 * 32;
#pragma unroll
  for (int c8 = 0; c8 < 4; c8++) {
    float4 f0 = *(const float4*)(Arow + c8 * 8);
    float4 f1 = *(const float4*)(Arow + c8 * 8 + 4);
    bf16x8 v;
    v[0] = (bf16)f0.x; v[1] = (bf16)f0.y; v[2] = (bf16)f0.z; v[3] = (bf16)f0.w;
    v[4] = (bf16)f1.x; v[5] = (bf16)f1.y; v[6] = (bf16)f1.z; v[7] = (bf16)f1.w;
    *(bf16x8*)(Xrow + q8 * 32 + c8 * 8) = v;
  }
  const bf16* Grow = agg + m * 256 + q8 * 32;
#pragma unroll
  for (int c8 = 0; c8 < 4; c8++)
    *(bf16x8*)(Xrow + 256 + q8 * 32 + c8 * 8) = *(const bf16x8*)(Grow + c8 * 8);
  __syncthreads();
  layer_inplace<16, 2, true>(X, 536, 280, Wf, n_fb);
  layer_inplace<8, 2, true>(X, 280, 280, Wh0, n_hb);
  layer_inplace<8, 2, true>(X, 280, 280, Wh1, n_hb + 256);
  f32x4 acc[2][4];
  layer_acc<8, 2>(X, 280, Wl, n_lb, acc);
  const int lane = t & 63;
  const int w = t >> 6;
  const int q = lane >> 4;
  const int c = lane & 15;
#pragma unroll
  for (int mt = 0; mt < 2; mt++)
#pragma unroll
    for (int nt = 0; nt < 4; nt++)
#pragma unroll
      for (int i = 0; i < 4; i++) {
        int mm = blockIdx.x * 32 + mt * 16 + q * 4 + i;
        int col = w * 64 + nt * 16 + c;
        out_nodes[mm * 256 + col] = nodes[mm * 256 + col] + acc[mt][nt][i];
      }
}

// ---------------- launch ----------------
extern "C" void kernel_launch(void* const* d_in, const int* in_sizes, int n_in,
                              void* d_out, int out_size, void* d_ws,
                              size_t ws_size, hipStream_t stream) {
  const float* nodes = (const float*)d_in[0];
  const float* eattr = (const float*)d_in[1];
  const int* eidx = (const int*)d_in[2];
  const float* e_fw = (const float*)d_in[3];
  const float* e_fb = (const float*)d_in[4];
  const float* e_hw = (const float*)d_in[5];
  const float* e_hb = (const float*)d_in[6];
  const float* e_lw = (const float*)d_in[7];
  const float* e_lb = (const float*)d_in[8];
  const float* n_fw = (const float*)d_in[9];
  const float* n_fb = (const float*)d_in[10];
  const float* n_hw = (const float*)d_in[11];
  const float* n_hb = (const float*)d_in[12];
  const float* n_lw = (const float*)d_in[13];
  const float* n_lb = (const float*)d_in[14];

  // workspace map (bytes); total = 93,716,480
  char* ws = (char*)d_ws;
  bf16* Sb = (bf16*)(ws + 0);            // [16384][256]
  bf16* Pb = (bf16*)(ws + 8388608);      // [16384][256]
  bf16* Eb = (bf16*)(ws + 16777216);     // [131072][256]
  bf16* aggb = (bf16*)(ws + 83886080);   // [16384][256]
  bf16* wp = (bf16*)(ws + 92274688);
  bf16* w_self = wp;                     // 65536 elems
  bf16* w_nb = wp + 65536;
  bf16* w_ea = wp + 131072;
  bf16* w_eh0 = wp + 196608;
  bf16* w_eh1 = wp + 262144;
  bf16* w_el = wp + 327680;
  bf16* w_nf = wp + 393216;              // 131072 elems (K=512)
  bf16* w_nh0 = wp + 524288;
  bf16* w_nh1 = wp + 589824;
  bf16* w_nl = wp + 655360;

  float* out_nodes = (float*)d_out;
  float* out_edges = (float*)d_out + 4194304;  // after [B,NP,NL] nodes

  pack_w<<<256, 256, 0, stream>>>(e_fw, w_self, 8, 256);           // e_fw rows 0..255
  pack_w<<<256, 256, 0, stream>>>(e_fw + 65536, w_nb, 8, 256);     // rows 256..511
  pack_w<<<256, 256, 0, stream>>>(e_fw + 131072, w_ea, 8, 256);    // rows 512..767
  pack_w<<<256, 256, 0, stream>>>(e_hw, w_eh0, 8, 256);
  pack_w<<<256, 256, 0, stream>>>(e_hw + 65536, w_eh1, 8, 256);
  pack_w<<<256, 256, 0, stream>>>(e_lw, w_el, 8, 256);
  pack_w<<<512, 256, 0, stream>>>(n_fw, w_nf, 16, 256);
  pack_w<<<256, 256, 0, stream>>>(n_hw, w_nh0, 8, 256);
  pack_w<<<256, 256, 0, stream>>>(n_hw + 65536, w_nh1, 8, 256);
  pack_w<<<256, 256, 0, stream>>>(n_lw, w_nl, 8, 256);

  // S = nodes@Wa + e_fb ; P = nodes@Wb ; E = eattr@Wc   (raw, relu later)
  gemm_fp32in<<<256, 256, 0, stream>>>(nodes, w_self, e_fb, Sb);
  gemm_fp32in<<<256, 256, 0, stream>>>(nodes, w_nb, nullptr, Pb);
  gemm_fp32in<<<2048, 256, 0, stream>>>(eattr, w_ea, nullptr, Eb);

  edge_mlp<<<4096, 256, 0, stream>>>(Sb, Pb, Eb, eidx, w_eh0, w_eh1, w_el,
                                     e_hb, e_lb, aggb, out_edges);
  node_mlp<<<512, 256, 0, stream>>>(nodes, aggb, w_nf, w_nh0, w_nh1, w_nl,
                                    n_fb, n_hb, n_lb, out_nodes);
}

// Round 2
// 480.926 us; speedup vs baseline: 1.1551x; 1.1551x over previous
//
#include <hip/hip_runtime.h>
#include <hip/hip_bf16.h>

// GNN processor: NL=256, NP=8192, NV=16, B=2.
// R1: factored first edge layer (S/P/E gather trick) + fused MFMA MLPs. 555us.
//     edge_mlp at 21% occupancy: acc[4][4] = 64 AGPRs + 92 VGPRs -> 2 waves/SIMD.
// R2: 512-thread blocks, MT=2 (acc=32 regs) -> 4 waves/SIMD, 2 blocks/CU (50%);
//     merged 10 pack launches -> 1, 3 producer GEMMs -> 1. 4 launches total.

typedef __bf16 bf16;
typedef __bf16 bf16x8 __attribute__((ext_vector_type(8)));
typedef float f32x4 __attribute__((ext_vector_type(4)));

#define MFMA16(a, b, c) __builtin_amdgcn_mfma_f32_16x16x32_bf16((a), (b), (c), 0, 0, 0)

constexpr int kNP = 8192;
constexpr int kNV = 16;

// ---------------- weight packing (single launch, 10 segments) ----------------
// fp32 W[K][N] -> bf16 fragment-ready:
// dst[((nt*kd + ks)*64 + lane)*8 + j] = W[ks*32 + (lane>>4)*8 + j][nt*16 + (lane&15)]
__global__ __launch_bounds__(256) void pack_all(
    const float* __restrict__ e_fw, const float* __restrict__ e_hw,
    const float* __restrict__ e_lw, const float* __restrict__ n_fw,
    const float* __restrict__ n_hw, const float* __restrict__ n_lw,
    bf16* __restrict__ wp) {
  int t = blockIdx.x * 256 + threadIdx.x;  // 0..720895
  const float* src;
  int kd = 8, local;
  if (t < 196608) {            // w_self / w_nb / w_ea from e_fw (768x256)
    src = e_fw + (t >> 16) * 65536; local = t & 65535;
  } else if (t < 262144) { src = e_hw;           local = t - 196608;
  } else if (t < 327680) { src = e_hw + 65536;   local = t - 262144;
  } else if (t < 393216) { src = e_lw;           local = t - 327680;
  } else if (t < 524288) { src = n_fw;           local = t - 393216; kd = 16;
  } else if (t < 589824) { src = n_hw;           local = t - 524288;
  } else if (t < 655360) { src = n_hw + 65536;   local = t - 589824;
  } else               { src = n_lw;             local = t - 655360; }
  int j = local & 7;
  int l = (local >> 3) & 63;
  int r2 = local >> 9;
  int ks = r2 % kd;
  int nt = r2 / kd;
  int k = ks * 32 + ((l >> 4) << 3) + j;
  int n = (nt << 4) + (l & 15);
  wp[t] = (bf16)src[k * 256 + n];
}

// ---------------- MFMA layer primitives ----------------
// Block = 512 threads = 8 waves: wave w -> row-group wh=w>>2 (MT*16 rows at
// rowOff), col-group wc=w&3 (64 cols). X: LDS [rows][xs] bf16, xs=K+24 pad.
// A-frag: a[j] = X[rowOff + mt*16 + (lane&15)][ks*32 + (lane>>4)*8 + j]
// B-frag: lane-ordered packed global load (1KB coalesced burst, L2-hot).
// C/D:    col = lane&15, row = (lane>>4)*4 + i
template <int KD, int MT>
__device__ __forceinline__ void layer_acc(const bf16* X, int xs,
                                          const bf16* __restrict__ Wp,
                                          const float* __restrict__ bias,
                                          f32x4 (&acc)[MT][4], int rowOff,
                                          int wc) {
  const int lane = threadIdx.x & 63;
  const int q = lane >> 4;
  const int c = lane & 15;
#pragma unroll
  for (int nt = 0; nt < 4; nt++) {
    float bv = bias ? bias[wc * 64 + nt * 16 + c] : 0.0f;
#pragma unroll
    for (int mt = 0; mt < MT; mt++) {
      acc[mt][nt][0] = bv; acc[mt][nt][1] = bv;
      acc[mt][nt][2] = bv; acc[mt][nt][3] = bv;
    }
  }
#pragma unroll
  for (int ks = 0; ks < KD; ks++) {
    bf16x8 a[MT];
#pragma unroll
    for (int mt = 0; mt < MT; mt++)
      a[mt] = *(const bf16x8*)(X + (rowOff + mt * 16 + c) * xs + ks * 32 + q * 8);
    bf16x8 bb[4];
#pragma unroll
    for (int nt = 0; nt < 4; nt++)
      bb[nt] = *(const bf16x8*)(Wp + ((((wc * 4 + nt) * KD + ks) * 64 + lane) << 3));
#pragma unroll
    for (int mt = 0; mt < MT; mt++)
#pragma unroll
      for (int nt = 0; nt < 4; nt++)
        acc[mt][nt] = MFMA16(a[mt], bb[nt], acc[mt][nt]);
  }
}

template <int KD, int MT, bool RELU>
__device__ __forceinline__ void layer_inplace(bf16* X, int xs_r, int xs_w,
                                              const bf16* __restrict__ Wp,
                                              const float* __restrict__ bias,
                                              int rowOff, int wc) {
  f32x4 acc[MT][4];
  layer_acc<KD, MT>(X, xs_r, Wp, bias, acc, rowOff, wc);
  const int lane = threadIdx.x & 63;
  const int q = lane >> 4;
  const int c = lane & 15;
  __syncthreads();  // all waves done reading X before overwrite
#pragma unroll
  for (int mt = 0; mt < MT; mt++)
#pragma unroll
    for (int nt = 0; nt < 4; nt++)
#pragma unroll
      for (int i = 0; i < 4; i++) {
        float v = acc[mt][nt][i];
        if (RELU) v = fmaxf(v, 0.0f);
        X[(rowOff + mt * 16 + q * 4 + i) * xs_w + (wc * 64 + nt * 16 + c)] = (bf16)v;
      }
  __syncthreads();
}

// ---------------- merged S / P / E producer GEMM ----------------
// blocks 0..255 -> S = nodes@Wa + e_fb; 256..511 -> P = nodes@Wb;
// 512..2559 -> E = eattr@Wc. 64 rows/block.
__global__ __launch_bounds__(512, 4) void producer_gemm(
    const float* __restrict__ nodes, const float* __restrict__ eattr,
    const bf16* __restrict__ w_self, const bf16* __restrict__ w_nb,
    const bf16* __restrict__ w_ea, const float* __restrict__ e_fb,
    bf16* __restrict__ Sb, bf16* __restrict__ Pb, bf16* __restrict__ Eb) {
  __shared__ bf16 X[64 * 280];
  const int t = threadIdx.x;
  const int m0 = blockIdx.x * 64;
  const float* A; const float* bias = nullptr; const bf16* Wp; bf16* out;
  if (m0 < 16384)      { A = nodes + m0 * 256;           Wp = w_self; bias = e_fb; out = Sb + m0 * 256; }
  else if (m0 < 32768) { A = nodes + (m0 - 16384) * 256; Wp = w_nb;   out = Pb + (m0 - 16384) * 256; }
  else                 { A = eattr + (m0 - 32768) * 256; Wp = w_ea;   out = Eb + (m0 - 32768) * 256; }
  const int r = t >> 3;   // 64 rows, 8 threads/row
  const int q8 = t & 7;
#pragma unroll
  for (int c8 = 0; c8 < 4; c8++) {
    int col = q8 * 8 + c8 * 64;
    float4 f0 = *(const float4*)(A + r * 256 + col);
    float4 f1 = *(const float4*)(A + r * 256 + col + 4);
    bf16x8 v;
    v[0] = (bf16)f0.x; v[1] = (bf16)f0.y; v[2] = (bf16)f0.z; v[3] = (bf16)f0.w;
    v[4] = (bf16)f1.x; v[5] = (bf16)f1.y; v[6] = (bf16)f1.z; v[7] = (bf16)f1.w;
    *(bf16x8*)(X + r * 280 + col) = v;
  }
  __syncthreads();
  const int w = t >> 6;
  layer_inplace<8, 2, false>(X, 280, 280, Wp, bias, (w >> 2) * 32, w & 3);
#pragma unroll
  for (int c8 = 0; c8 < 4; c8++) {
    int col = q8 * 8 + c8 * 64;
    *(uint4*)(out + r * 256 + col) = *(const uint4*)(X + r * 280 + col);
  }
}

// ---------------- fused edge MLP (layers 2..4) + aggregation ----------------
// Row e = ((b*NP + p)*NV + v). Block = 64 rows = 4 complete (b,p) groups.
__global__ __launch_bounds__(512, 4) void edge_mlp(
    const bf16* __restrict__ S, const bf16* __restrict__ P,
    const bf16* __restrict__ E, const int* __restrict__ idx,
    const bf16* __restrict__ Wh0, const bf16* __restrict__ Wh1,
    const bf16* __restrict__ Wl, const float* __restrict__ e_hb,
    const float* __restrict__ e_lb, bf16* __restrict__ agg,
    float* __restrict__ out_edges) {
  __shared__ bf16 X[64 * 280];
  const int t = threadIdx.x;
  const int e0 = blockIdx.x * 64;
  const int b = e0 >> 17;                 // 131072 edges per batch
  const int pbase = (e0 >> 4) & (kNP - 1);
  {
    const int r = t >> 3;   // 64 rows, 8 threads/row
    const int q8 = t & 7;
    const int p = pbase + (r >> 4);
    const int v = r & 15;
    const int nb = idx[p * kNV + v];
    const bf16* Srow = S + ((b << 13) + p) * 256;
    const bf16* Prow = P + ((b << 13) + nb) * 256;
    const bf16* Erow = E + (p * kNV + v) * 256;
#pragma unroll
    for (int c8 = 0; c8 < 4; c8++) {
      int col = q8 * 8 + c8 * 64;
      bf16x8 sv = *(const bf16x8*)(Srow + col);
      bf16x8 pv = *(const bf16x8*)(Prow + col);
      bf16x8 ev = *(const bf16x8*)(Erow + col);
      bf16x8 o;
#pragma unroll
      for (int j = 0; j < 8; j++) {
        float f = (float)sv[j] + (float)pv[j] + (float)ev[j];
        o[j] = (bf16)fmaxf(f, 0.0f);  // relu(layer-1)
      }
      *(bf16x8*)(X + r * 280 + col) = o;
    }
  }
  __syncthreads();
  const int w = t >> 6;
  const int wc = w & 3;
  const int rowOff = (w >> 2) * 32;
  layer_inplace<8, 2, true>(X, 280, 280, Wh0, e_hb, rowOff, wc);
  layer_inplace<8, 2, true>(X, 280, 280, Wh1, e_hb + 256, rowOff, wc);
  f32x4 acc[2][4];
  layer_acc<8, 2>(X, 280, Wl, e_lb, acc, rowOff, wc);
  const int lane = t & 63;
  const int q = lane >> 4;
  const int c = lane & 15;
  // NV-aggregation: each 16-row M-tile is one (b,p) group; rows are v.
#pragma unroll
  for (int mt = 0; mt < 2; mt++) {
#pragma unroll
    for (int nt = 0; nt < 4; nt++) {
      float s = acc[mt][nt][0] + acc[mt][nt][1] + acc[mt][nt][2] + acc[mt][nt][3];
      s += __shfl_xor(s, 16, 64);
      s += __shfl_xor(s, 32, 64);
      if (lane < 16)
        agg[((b << 13) + pbase + (rowOff >> 4) + mt) * 256 + wc * 64 + nt * 16 + lane] = (bf16)s;
    }
  }
  if (b == 0) {  // only batch-0 edges are outputs
#pragma unroll
    for (int mt = 0; mt < 2; mt++)
#pragma unroll
      for (int nt = 0; nt < 4; nt++)
#pragma unroll
        for (int i = 0; i < 4; i++) {
          int e = e0 + rowOff + mt * 16 + q * 4 + i;
          out_edges[e * 256 + (wc * 64 + nt * 16 + c)] = acc[mt][nt][i];
        }
  }
}

// ---------------- fused node MLP + residual ----------------
// 32-row tiles, 512 threads (8 waves: 2 row-groups x 4 col-groups, MT=1).
__global__ __launch_bounds__(512, 4) void node_mlp(
    const float* __restrict__ nodes, const bf16* __restrict__ agg,
    const bf16* __restrict__ Wf, const bf16* __restrict__ Wh0,
    const bf16* __restrict__ Wh1, const bf16* __restrict__ Wl,
    const float* __restrict__ n_fb, const float* __restrict__ n_hb,
    const float* __restrict__ n_lb, float* __restrict__ out_nodes) {
  __shared__ bf16 X[32 * 536];
  const int t = threadIdx.x;
  const int r = t >> 4;   // 32 rows, 16 threads/row
  const int q16 = t & 15;
  const int m = blockIdx.x * 32 + r;
#pragma unroll
  for (int c8 = 0; c8 < 4; c8++) {
    int col = q16 * 8 + c8 * 128;  // 0..511; <256 from nodes, >=256 from agg
    if (col < 256) {
      float4 f0 = *(const float4*)(nodes + m * 256 + col);
      float4 f1 = *(const float4*)(nodes + m * 256 + col + 4);
      bf16x8 v;
      v[0] = (bf16)f0.x; v[1] = (bf16)f0.y; v[2] = (bf16)f0.z; v[3] = (bf16)f0.w;
      v[4] = (bf16)f1.x; v[5] = (bf16)f1.y; v[6] = (bf16)f1.z; v[7] = (bf16)f1.w;
      *(bf16x8*)(X + r * 536 + col) = v;
    } else {
      *(bf16x8*)(X + r * 536 + col) =
          *(const bf16x8*)(agg + m * 256 + (col - 256));
    }
  }
  __syncthreads();
  const int w = t >> 6;
  const int wc = w & 3;
  const int rowOff = (w >> 2) * 16;
  layer_inplace<16, 1, true>(X, 536, 280, Wf, n_fb, rowOff, wc);
  layer_inplace<8, 1, true>(X, 280, 280, Wh0, n_hb, rowOff, wc);
  layer_inplace<8, 1, true>(X, 280, 280, Wh1, n_hb + 256, rowOff, wc);
  f32x4 acc[1][4];
  layer_acc<8, 1>(X, 280, Wl, n_lb, acc, rowOff, wc);
  const int lane = t & 63;
  const int q = lane >> 4;
  const int c = lane & 15;
#pragma unroll
  for (int nt = 0; nt < 4; nt++)
#pragma unroll
    for (int i = 0; i < 4; i++) {
      int mm = blockIdx.x * 32 + rowOff + q * 4 + i;
      int col = wc * 64 + nt * 16 + c;
      out_nodes[mm * 256 + col] = nodes[mm * 256 + col] + acc[0][nt][i];
    }
}

// ---------------- launch ----------------
extern "C" void kernel_launch(void* const* d_in, const int* in_sizes, int n_in,
                              void* d_out, int out_size, void* d_ws,
                              size_t ws_size, hipStream_t stream) {
  const float* nodes = (const float*)d_in[0];
  const float* eattr = (const float*)d_in[1];
  const int* eidx = (const int*)d_in[2];
  const float* e_fw = (const float*)d_in[3];
  const float* e_fb = (const float*)d_in[4];
  const float* e_hw = (const float*)d_in[5];
  const float* e_hb = (const float*)d_in[6];
  const float* e_lw = (const float*)d_in[7];
  const float* e_lb = (const float*)d_in[8];
  const float* n_fw = (const float*)d_in[9];
  const float* n_fb = (const float*)d_in[10];
  const float* n_hw = (const float*)d_in[11];
  const float* n_hb = (const float*)d_in[12];
  const float* n_lw = (const float*)d_in[13];
  const float* n_lb = (const float*)d_in[14];

  // workspace map (bytes); total = 93,716,480
  char* ws = (char*)d_ws;
  bf16* Sb = (bf16*)(ws + 0);            // [16384][256]
  bf16* Pb = (bf16*)(ws + 8388608);      // [16384][256]
  bf16* Eb = (bf16*)(ws + 16777216);     // [131072][256]
  bf16* aggb = (bf16*)(ws + 83886080);   // [16384][256]
  bf16* wp = (bf16*)(ws + 92274688);
  bf16* w_self = wp;                     // packed-weight arena, 720896 elems
  bf16* w_nb = wp + 65536;
  bf16* w_ea = wp + 131072;
  bf16* w_eh0 = wp + 196608;
  bf16* w_eh1 = wp + 262144;
  bf16* w_el = wp + 327680;
  bf16* w_nf = wp + 393216;              // 131072 elems (K=512)
  bf16* w_nh0 = wp + 524288;
  bf16* w_nh1 = wp + 589824;
  bf16* w_nl = wp + 655360;

  float* out_nodes = (float*)d_out;
  float* out_edges = (float*)d_out + 4194304;  // after [B,NP,NL] nodes

  pack_all<<<2816, 256, 0, stream>>>(e_fw, e_hw, e_lw, n_fw, n_hw, n_lw, wp);
  producer_gemm<<<2560, 512, 0, stream>>>(nodes, eattr, w_self, w_nb, w_ea,
                                          e_fb, Sb, Pb, Eb);
  edge_mlp<<<4096, 512, 0, stream>>>(Sb, Pb, Eb, eidx, w_eh0, w_eh1, w_el,
                                     e_hb, e_lb, aggb, out_edges);
  node_mlp<<<512, 512, 0, stream>>>(nodes, aggb, w_nf, w_nh0, w_nh1, w_nl,
                                    n_fb, n_hb, n_lb, out_nodes);
}

// Round 3
// 471.889 us; speedup vs baseline: 1.1772x; 1.0192x over previous
//
#include <hip/hip_runtime.h>
#include <hip/hip_bf16.h>

// GNN processor: NL=256, NP=8192, NV=16, B=2.
// R1: factored first edge layer (S/P/E gather trick) + fused MFMA MLPs. 555us.
// R2: 512-thread/MT=2 blocks (43% occ), merged launches. 481us.
// R3: E-GEMM inlined into edge_mlp (block = 2 points x 16v x 2 batches ->
//     E computed once, eattr read once chip-wide, Eb round-trip deleted,
//     producer shrinks 2560->256 blocks doing S+P from one staged tile).

typedef __bf16 bf16;
typedef __bf16 bf16x8 __attribute__((ext_vector_type(8)));
typedef float f32x4 __attribute__((ext_vector_type(4)));

#define MFMA16(a, b, c) __builtin_amdgcn_mfma_f32_16x16x32_bf16((a), (b), (c), 0, 0, 0)

constexpr int kNP = 8192;
constexpr int kNV = 16;

// ---------------- weight packing (single launch, 10 segments) ----------------
// fp32 W[K][N] -> bf16 fragment-ready:
// dst[((nt*kd + ks)*64 + lane)*8 + j] = W[ks*32 + (lane>>4)*8 + j][nt*16 + (lane&15)]
__global__ __launch_bounds__(256) void pack_all(
    const float* __restrict__ e_fw, const float* __restrict__ e_hw,
    const float* __restrict__ e_lw, const float* __restrict__ n_fw,
    const float* __restrict__ n_hw, const float* __restrict__ n_lw,
    bf16* __restrict__ wp) {
  int t = blockIdx.x * 256 + threadIdx.x;  // 0..720895
  const float* src;
  int kd = 8, local;
  if (t < 196608) {            // w_self / w_nb / w_ea from e_fw (768x256)
    src = e_fw + (t >> 16) * 65536; local = t & 65535;
  } else if (t < 262144) { src = e_hw;           local = t - 196608;
  } else if (t < 327680) { src = e_hw + 65536;   local = t - 262144;
  } else if (t < 393216) { src = e_lw;           local = t - 327680;
  } else if (t < 524288) { src = n_fw;           local = t - 393216; kd = 16;
  } else if (t < 589824) { src = n_hw;           local = t - 524288;
  } else if (t < 655360) { src = n_hw + 65536;   local = t - 589824;
  } else               { src = n_lw;             local = t - 655360; }
  int j = local & 7;
  int l = (local >> 3) & 63;
  int r2 = local >> 9;
  int ks = r2 % kd;
  int nt = r2 / kd;
  int k = ks * 32 + ((l >> 4) << 3) + j;
  int n = (nt << 4) + (l & 15);
  wp[t] = (bf16)src[k * 256 + n];
}

// ---------------- MFMA layer primitives ----------------
// 512-thread block = 8 waves: wave w -> row-group rg=w>>2, col-group wc=w&3.
// X: LDS [rows][280] bf16 (K+24 pad). A-frag from LDS, B-frag lane-ordered
// packed global load (1KB coalesced, L2-hot).
// C/D: col = lane&15, row = (lane>>4)*4 + i
template <int KD, int MT>
__device__ __forceinline__ void layer_acc(const bf16* X, int xs,
                                          const bf16* __restrict__ Wp,
                                          const float* __restrict__ bias,
                                          f32x4 (&acc)[MT][4], int rowOff,
                                          int wc) {
  const int lane = threadIdx.x & 63;
  const int q = lane >> 4;
  const int c = lane & 15;
#pragma unroll
  for (int nt = 0; nt < 4; nt++) {
    float bv = bias ? bias[wc * 64 + nt * 16 + c] : 0.0f;
#pragma unroll
    for (int mt = 0; mt < MT; mt++) {
      acc[mt][nt][0] = bv; acc[mt][nt][1] = bv;
      acc[mt][nt][2] = bv; acc[mt][nt][3] = bv;
    }
  }
#pragma unroll
  for (int ks = 0; ks < KD; ks++) {
    bf16x8 a[MT];
#pragma unroll
    for (int mt = 0; mt < MT; mt++)
      a[mt] = *(const bf16x8*)(X + (rowOff + mt * 16 + c) * xs + ks * 32 + q * 8);
    bf16x8 bb[4];
#pragma unroll
    for (int nt = 0; nt < 4; nt++)
      bb[nt] = *(const bf16x8*)(Wp + ((((wc * 4 + nt) * KD + ks) * 64 + lane) << 3));
#pragma unroll
    for (int mt = 0; mt < MT; mt++)
#pragma unroll
      for (int nt = 0; nt < 4; nt++)
        acc[mt][nt] = MFMA16(a[mt], bb[nt], acc[mt][nt]);
  }
}

template <int KD, int MT, bool RELU>
__device__ __forceinline__ void layer_inplace(bf16* X, int xs_r, int xs_w,
                                              const bf16* __restrict__ Wp,
                                              const float* __restrict__ bias,
                                              int rowOff, int wc) {
  f32x4 acc[MT][4];
  layer_acc<KD, MT>(X, xs_r, Wp, bias, acc, rowOff, wc);
  const int lane = threadIdx.x & 63;
  const int q = lane >> 4;
  const int c = lane & 15;
  __syncthreads();  // all waves done reading X before overwrite
#pragma unroll
  for (int mt = 0; mt < MT; mt++)
#pragma unroll
    for (int nt = 0; nt < 4; nt++)
#pragma unroll
      for (int i = 0; i < 4; i++) {
        float v = acc[mt][nt][i];
        if (RELU) v = fmaxf(v, 0.0f);
        X[(rowOff + mt * 16 + q * 4 + i) * xs_w + (wc * 64 + nt * 16 + c)] = (bf16)v;
      }
  __syncthreads();
}

// ---------------- S+P producer: one staged tile, two GEMMs ----------------
// 256 blocks x 64 rows: S = nodes@Wa + e_fb ; P = nodes@Wb. Direct acc->global.
__global__ __launch_bounds__(512, 4) void producer_sp(
    const float* __restrict__ nodes, const bf16* __restrict__ w_self,
    const bf16* __restrict__ w_nb, const float* __restrict__ e_fb,
    bf16* __restrict__ Sb, bf16* __restrict__ Pb) {
  __shared__ bf16 X[64 * 280];
  const int t = threadIdx.x;
  const int m0 = blockIdx.x * 64;
  {
    const int r = t >> 3;   // 64 rows, 8 threads/row
    const int q8 = t & 7;
#pragma unroll
    for (int c8 = 0; c8 < 4; c8++) {
      int col = q8 * 8 + c8 * 64;
      float4 f0 = *(const float4*)(nodes + (m0 + r) * 256 + col);
      float4 f1 = *(const float4*)(nodes + (m0 + r) * 256 + col + 4);
      bf16x8 v;
      v[0] = (bf16)f0.x; v[1] = (bf16)f0.y; v[2] = (bf16)f0.z; v[3] = (bf16)f0.w;
      v[4] = (bf16)f1.x; v[5] = (bf16)f1.y; v[6] = (bf16)f1.z; v[7] = (bf16)f1.w;
      *(bf16x8*)(X + r * 280 + col) = v;
    }
  }
  __syncthreads();
  const int lane = t & 63;
  const int w = t >> 6;
  const int wc = w & 3;
  const int rowOff = (w >> 2) * 32;
  const int q = lane >> 4;
  const int c = lane & 15;
  f32x4 acc[2][4];
  layer_acc<8, 2>(X, 280, w_self, e_fb, acc, rowOff, wc);
#pragma unroll
  for (int mt = 0; mt < 2; mt++)
#pragma unroll
    for (int nt = 0; nt < 4; nt++)
#pragma unroll
      for (int i = 0; i < 4; i++)
        Sb[(m0 + rowOff + mt * 16 + q * 4 + i) * 256 + wc * 64 + nt * 16 + c] =
            (bf16)acc[mt][nt][i];
  layer_acc<8, 2>(X, 280, w_nb, nullptr, acc, rowOff, wc);
#pragma unroll
  for (int mt = 0; mt < 2; mt++)
#pragma unroll
    for (int nt = 0; nt < 4; nt++)
#pragma unroll
      for (int i = 0; i < 4; i++)
        Pb[(m0 + rowOff + mt * 16 + q * 4 + i) * 256 + wc * 64 + nt * 16 + c] =
            (bf16)acc[mt][nt][i];
}

// ---------------- fused edge MLP: inline E + layers 2..4 + aggregation ------
// Block = 2 points x 16 v x 2 batches = 64 rows. E (32 rows) computed once,
// shared by both batches. X rows 0-31 = b0 edges, 32-63 = b1 edges.
__global__ __launch_bounds__(512, 4) void edge_mlp(
    const bf16* __restrict__ S, const bf16* __restrict__ P,
    const float* __restrict__ eattr, const int* __restrict__ idx,
    const bf16* __restrict__ w_ea, const bf16* __restrict__ Wh0,
    const bf16* __restrict__ Wh1, const bf16* __restrict__ Wl,
    const float* __restrict__ e_hb, const float* __restrict__ e_lb,
    bf16* __restrict__ agg, float* __restrict__ out_edges) {
  __shared__ bf16 X[64 * 280];
  const int t = threadIdx.x;
  const int pbase = blockIdx.x * 2;  // 4096 blocks
  // ---- stage eattr (32 rows fp32) into X rows 32..63 as bf16
  {
    const int r = t >> 4;     // 0..31
    const int q16 = t & 15;   // 16 cols each
    const float* src = eattr + (pbase * 16 + r) * 256 + q16 * 16;
    bf16* dst = X + (32 + r) * 280 + q16 * 16;
    float4 f0 = *(const float4*)(src);
    float4 f1 = *(const float4*)(src + 4);
    float4 f2 = *(const float4*)(src + 8);
    float4 f3 = *(const float4*)(src + 12);
    bf16x8 v0, v1;
    v0[0] = (bf16)f0.x; v0[1] = (bf16)f0.y; v0[2] = (bf16)f0.z; v0[3] = (bf16)f0.w;
    v0[4] = (bf16)f1.x; v0[5] = (bf16)f1.y; v0[6] = (bf16)f1.z; v0[7] = (bf16)f1.w;
    v1[0] = (bf16)f2.x; v1[1] = (bf16)f2.y; v1[2] = (bf16)f2.z; v1[3] = (bf16)f2.w;
    v1[4] = (bf16)f3.x; v1[5] = (bf16)f3.y; v1[6] = (bf16)f3.z; v1[7] = (bf16)f3.w;
    *(bf16x8*)(dst) = v0;
    *(bf16x8*)(dst + 8) = v1;
  }
  __syncthreads();
  const int lane = t & 63;
  const int w = t >> 6;
  const int wc = w & 3;
  const int rg = w >> 2;
  const int q = lane >> 4;
  const int c = lane & 15;
  // ---- inline E-GEMM over the 32 staged rows (E = eattr @ Wc, no bias)
  {
    f32x4 acce[1][4];
    layer_acc<8, 1>(X, 280, w_ea, nullptr, acce, 32 + rg * 16, wc);
    __syncthreads();  // all A-frag reads done before in-place E write
#pragma unroll
    for (int nt = 0; nt < 4; nt++)
#pragma unroll
      for (int i = 0; i < 4; i++)
        X[(32 + rg * 16 + q * 4 + i) * 280 + wc * 64 + nt * 16 + c] =
            (bf16)acce[0][nt][i];
  }
  __syncthreads();
  // ---- assemble relu(S + Pgather + E) for both batches
  {
    const int r = t >> 3;     // 0..63
    const int q8 = t & 7;     // 32 cols each
    const int b = r >> 5;
    const int rr = r & 31;
    const int p = pbase + (rr >> 4);
    const int v = rr & 15;
    const int nb = idx[p * kNV + v];
    const bf16* Srow = S + ((b << 13) + p) * 256;
    const bf16* Prow = P + ((b << 13) + nb) * 256;
    bf16x8 hold[4];
#pragma unroll
    for (int j = 0; j < 4; j++) {
      int col = q8 * 32 + j * 8;
      bf16x8 ev = *(const bf16x8*)(X + (32 + rr) * 280 + col);
      bf16x8 sv = *(const bf16x8*)(Srow + col);
      bf16x8 pv = *(const bf16x8*)(Prow + col);
      bf16x8 o;
#pragma unroll
      for (int k = 0; k < 8; k++) {
        float f = (float)sv[k] + (float)pv[k] + (float)ev[k];
        o[k] = (bf16)fmaxf(f, 0.0f);
      }
      hold[j] = o;
    }
    __syncthreads();  // E reads done everywhere before rows are overwritten
#pragma unroll
    for (int j = 0; j < 4; j++)
      *(bf16x8*)(X + r * 280 + q8 * 32 + j * 8) = hold[j];
  }
  __syncthreads();
  // ---- hidden layers + last layer
  layer_inplace<8, 2, true>(X, 280, 280, Wh0, e_hb, rg * 32, wc);
  layer_inplace<8, 2, true>(X, 280, 280, Wh1, e_hb + 256, rg * 32, wc);
  f32x4 acc[2][4];
  layer_acc<8, 2>(X, 280, Wl, e_lb, acc, rg * 32, wc);
  // ---- NV-aggregation: tile g = rg*2+mt -> batch g>>1, point pbase+(g&1)
#pragma unroll
  for (int mt = 0; mt < 2; mt++) {
    const int g = rg * 2 + mt;
#pragma unroll
    for (int nt = 0; nt < 4; nt++) {
      float s = acc[mt][nt][0] + acc[mt][nt][1] + acc[mt][nt][2] + acc[mt][nt][3];
      s += __shfl_xor(s, 16, 64);
      s += __shfl_xor(s, 32, 64);
      if (lane < 16)
        agg[(((g >> 1) << 13) + pbase + (g & 1)) * 256 + wc * 64 + nt * 16 + lane] =
            (bf16)s;
    }
  }
  // ---- batch-0 edge outputs (rows 0..31 = rg 0)
  if (rg == 0) {
#pragma unroll
    for (int mt = 0; mt < 2; mt++)
#pragma unroll
      for (int nt = 0; nt < 4; nt++)
#pragma unroll
        for (int i = 0; i < 4; i++) {
          int e = (pbase + mt) * kNV + q * 4 + i;
          out_edges[e * 256 + wc * 64 + nt * 16 + c] = acc[mt][nt][i];
        }
  }
}

// ---------------- fused node MLP + residual ----------------
// 32-row tiles, 512 threads (8 waves: 2 row-groups x 4 col-groups, MT=1).
__global__ __launch_bounds__(512, 4) void node_mlp(
    const float* __restrict__ nodes, const bf16* __restrict__ agg,
    const bf16* __restrict__ Wf, const bf16* __restrict__ Wh0,
    const bf16* __restrict__ Wh1, const bf16* __restrict__ Wl,
    const float* __restrict__ n_fb, const float* __restrict__ n_hb,
    const float* __restrict__ n_lb, float* __restrict__ out_nodes) {
  __shared__ bf16 X[32 * 536];
  const int t = threadIdx.x;
  const int r = t >> 4;   // 32 rows, 16 threads/row
  const int q16 = t & 15;
  const int m = blockIdx.x * 32 + r;
#pragma unroll
  for (int c8 = 0; c8 < 4; c8++) {
    int col = q16 * 8 + c8 * 128;  // 0..511; <256 from nodes, >=256 from agg
    if (col < 256) {
      float4 f0 = *(const float4*)(nodes + m * 256 + col);
      float4 f1 = *(const float4*)(nodes + m * 256 + col + 4);
      bf16x8 v;
      v[0] = (bf16)f0.x; v[1] = (bf16)f0.y; v[2] = (bf16)f0.z; v[3] = (bf16)f0.w;
      v[4] = (bf16)f1.x; v[5] = (bf16)f1.y; v[6] = (bf16)f1.z; v[7] = (bf16)f1.w;
      *(bf16x8*)(X + r * 536 + col) = v;
    } else {
      *(bf16x8*)(X + r * 536 + col) =
          *(const bf16x8*)(agg + m * 256 + (col - 256));
    }
  }
  __syncthreads();
  const int w = t >> 6;
  const int wc = w & 3;
  const int rowOff = (w >> 2) * 16;
  layer_inplace<16, 1, true>(X, 536, 280, Wf, n_fb, rowOff, wc);
  layer_inplace<8, 1, true>(X, 280, 280, Wh0, n_hb, rowOff, wc);
  layer_inplace<8, 1, true>(X, 280, 280, Wh1, n_hb + 256, rowOff, wc);
  f32x4 acc[1][4];
  layer_acc<8, 1>(X, 280, Wl, n_lb, acc, rowOff, wc);
  const int lane = t & 63;
  const int q = lane >> 4;
  const int c = lane & 15;
#pragma unroll
  for (int nt = 0; nt < 4; nt++)
#pragma unroll
    for (int i = 0; i < 4; i++) {
      int mm = blockIdx.x * 32 + rowOff + q * 4 + i;
      int col = wc * 64 + nt * 16 + c;
      out_nodes[mm * 256 + col] = nodes[mm * 256 + col] + acc[0][nt][i];
    }
}

// ---------------- launch ----------------
extern "C" void kernel_launch(void* const* d_in, const int* in_sizes, int n_in,
                              void* d_out, int out_size, void* d_ws,
                              size_t ws_size, hipStream_t stream) {
  const float* nodes = (const float*)d_in[0];
  const float* eattr = (const float*)d_in[1];
  const int* eidx = (const int*)d_in[2];
  const float* e_fw = (const float*)d_in[3];
  const float* e_fb = (const float*)d_in[4];
  const float* e_hw = (const float*)d_in[5];
  const float* e_hb = (const float*)d_in[6];
  const float* e_lw = (const float*)d_in[7];
  const float* e_lb = (const float*)d_in[8];
  const float* n_fw = (const float*)d_in[9];
  const float* n_fb = (const float*)d_in[10];
  const float* n_hw = (const float*)d_in[11];
  const float* n_hb = (const float*)d_in[12];
  const float* n_lw = (const float*)d_in[13];
  const float* n_lb = (const float*)d_in[14];

  // workspace map (bytes); total ~26.6 MB
  char* ws = (char*)d_ws;
  bf16* Sb = (bf16*)(ws + 0);            // [16384][256]
  bf16* Pb = (bf16*)(ws + 8388608);      // [16384][256]
  bf16* aggb = (bf16*)(ws + 16777216);   // [16384][256]
  bf16* wp = (bf16*)(ws + 25165824);     // packed-weight arena, 720896 elems
  bf16* w_self = wp;
  bf16* w_nb = wp + 65536;
  bf16* w_ea = wp + 131072;
  bf16* w_eh0 = wp + 196608;
  bf16* w_eh1 = wp + 262144;
  bf16* w_el = wp + 327680;
  bf16* w_nf = wp + 393216;              // 131072 elems (K=512)
  bf16* w_nh0 = wp + 524288;
  bf16* w_nh1 = wp + 589824;
  bf16* w_nl = wp + 655360;

  float* out_nodes = (float*)d_out;
  float* out_edges = (float*)d_out + 4194304;  // after [B,NP,NL] nodes

  pack_all<<<2816, 256, 0, stream>>>(e_fw, e_hw, e_lw, n_fw, n_hw, n_lw, wp);
  producer_sp<<<256, 512, 0, stream>>>(nodes, w_self, w_nb, e_fb, Sb, Pb);
  edge_mlp<<<4096, 512, 0, stream>>>(Sb, Pb, eattr, eidx, w_ea, w_eh0, w_eh1,
                                     w_el, e_hb, e_lb, aggb, out_edges);
  node_mlp<<<512, 512, 0, stream>>>(nodes, aggb, w_nf, w_nh0, w_nh1, w_nl,
                                    n_fb, n_hb, n_lb, out_nodes);
}